// Round 11
// baseline (125.086 us; speedup 1.0000x reference)
//
#include <hip/hip_runtime.h>

#define BATCH 8
#define NN 32768
#define KK 128
#define NCHUNK 64
#define CHUNK 512             // NN / NCHUNK
#define NST 8                 // super-tiles of 64 n per chunk
#define NITER 8               // CG iterations (kappa ~1.4)

typedef __attribute__((ext_vector_type(8)))  _Float16 half8;
typedef __attribute__((ext_vector_type(4)))  _Float16 half4;
typedef __attribute__((ext_vector_type(16))) float    f32x16;

// ---- workspace byte offsets (~21.0 MB) ----
#define MT_OFF   0ull                      // multT fp16 [128][32768]
#define WH_OFF   8388608ull                // wh fp16 [8][32768]
#define GP_OFF   8912896ull                // Gp fp16 [8][64][10][1024]
#define MP2_OFF  19398656ull               // Mp2 f32 [8][128][256]  (m partials per n-block)
#define MG_OFF   20447232ull               // Mg  f32 [8][128]
#define G_OFF    20451328ull               // G   f32 [8][128][128]

// ---------------------------------------------------------------------------
// K0: fused conv + transpose + m-partials.
//  * mask -> fp16 WH (gram needs it); data folded directly into wd = w*d (f32)
//  * mult f32 [N][K] -> multT fp16 [K][N] (XOR-swizzled LDS, coalesced writes)
//  * NEW: m-partials  m_k = sum_n wd[b][n]*mult[n][k]  per 128-n block
//    (evicted from gram: R8 PMC showed gram VALUBusy 23.5% > MfmaUtil 16.8%)
// ---------------------------------------------------------------------------
__global__ __launch_bounds__(256) void prep_kernel(
    const float* __restrict__ data, const float* __restrict__ mask,
    const float* __restrict__ mult, unsigned char* __restrict__ ws)
{
    __shared__ _Float16 t[128][136];
    __shared__ float wd[8][128];
    const int tid = threadIdx.x;
    const int n0  = blockIdx.x * 128;

    {
        const int bb = tid >> 5, q = tid & 31;
        const size_t src = (size_t)bb * NN + n0 + q * 4;
        const float4 d4 = *(const float4*)(data + src);
        const float4 m4 = *(const float4*)(mask + src);
        half4 wv = { (_Float16)m4.x, (_Float16)m4.y, (_Float16)m4.z, (_Float16)m4.w };
        *(half4*)((_Float16*)(ws + WH_OFF) + src) = wv;
        *(float4*)&wd[bb][q * 4] = make_float4(m4.x * d4.x, m4.y * d4.y,
                                               m4.z * d4.z, m4.w * d4.w);
    }

    const float4* m4p = (const float4*)mult;
#pragma unroll
    for (int u = 0; u < 16; ++u) {
        const int c16 = u * 256 + tid;
        const int n  = c16 >> 5;
        const int kq = c16 & 31;
        float4 v = m4p[(size_t)(n0 + n) * 32 + kq];
        half4 h = { (_Float16)v.x, (_Float16)v.y, (_Float16)v.z, (_Float16)v.w };
        const int c4s = kq ^ ((n >> 3) & 7);
        *(half4*)&t[n][c4s * 4] = h;
    }
    __syncthreads();

    // coalesced transposed global write
    _Float16* mt = (_Float16*)(ws + MT_OFF);
    const int g = tid & 15;
#pragma unroll
    for (int i = 0; i < 8; ++i) {
        const int k = (tid >> 4) + i * 16;
        half8 v;
#pragma unroll
        for (int j = 0; j < 8; ++j) {
            const int n = g * 8 + j;
            const int cs = (k >> 2) ^ ((n >> 3) & 7);
            v[j] = t[n][cs * 4 + (k & 3)];
        }
        *(half8*)(mt + (size_t)k * NN + n0 + g * 8) = v;
    }

    // m-partials: thread (bb, kq) owns k = 4*kq..4*kq+3 for batch bb
    {
        const int bb = tid >> 5, kq = tid & 31;
        float m0 = 0.f, m1 = 0.f, m2 = 0.f, m3 = 0.f;
#pragma unroll 16
        for (int nl = 0; nl < 128; ++nl) {
            const float wdv = wd[bb][nl];
            const int slot = kq ^ ((nl >> 3) & 7);
            half4 hv = *(const half4*)&t[nl][slot * 4];
            m0 = fmaf((float)hv[0], wdv, m0);
            m1 = fmaf((float)hv[1], wdv, m1);
            m2 = fmaf((float)hv[2], wdv, m2);
            m3 = fmaf((float)hv[3], wdv, m3);
        }
        float* Mp2 = (float*)(ws + MP2_OFF) + ((size_t)bb * KK + kq * 4) * 256 + blockIdx.x;
        Mp2[0]   = m0;
        Mp2[256] = m1;
        Mp2[512] = m2;
        Mp2[768] = m3;
    }
}

// ---------------------------------------------------------------------------
// K1: MFMA gram partials — BARRIER-FREE main loop.
//  * fragments read DIRECTLY from multT in global/L2 (bit-identical values to
//    the old LDS-staged path), ping-pong register prefetch 1 st ahead
//  * no m-work, no d/tile staging -> ~220 regs/wave -> launch_bounds(256,2)
//    fits WITHOUT spills (R10 spilled: 284-reg demand under a 256 cap)
//  * NCHUNK=64 -> 512 blocks -> 2 independent blocks/CU (TLP hides L2/L3
//    latency; R9 showed more waves on ONE barrier doesn't)
//  * epilogue: [c2][lane] conflict-free layout (validated R9/R10)
// ---------------------------------------------------------------------------
__global__ __launch_bounds__(256, 2) void gram_kernel(
    unsigned char* __restrict__ ws)
{
    __shared__ unsigned char smem[33792];   // [0,32K) epilogue Rb | [32K,+1K) w
    const int tid = threadIdx.x;
    const int b     = blockIdx.x >> 6;
    const int chunk = blockIdx.x & 63;
    const int n0    = chunk * CHUNK;
    const int w  = tid >> 6;
    const int l  = tid & 63;
    const int hi = l >> 5;

    const _Float16* mt = (const _Float16*)(ws + MT_OFF);
    _Float16* wls = (_Float16*)(smem + 32768);

    if (tid < 64) {
        half8 wv = *(const half8*)((const _Float16*)(ws + WH_OFF) + (size_t)b * NN + n0 + tid * 8);
        *(half8*)(wls + tid * 8) = wv;
    }
    __syncthreads();

    // per-lane fragment base: row = (l&31) (+32/64/96 per frag), n = n0 + st*64 + (w*2+hi)*8
    const _Float16* p0 = mt + (size_t)(l & 31) * NN + n0 + (w * 2 + hi) * 8;
    const size_t o1 = (size_t)32 * NN, o2 = (size_t)64 * NN, o3 = (size_t)96 * NN;

    f32x16 a00 = {}, a01 = {}, a02 = {}, a03 = {}, a11 = {},
           a12 = {}, a13 = {}, a22 = {}, a23 = {}, a33 = {};

    half8 F0 = *(const half8*)(p0);
    half8 F1 = *(const half8*)(p0 + o1);
    half8 F2 = *(const half8*)(p0 + o2);
    half8 F3 = *(const half8*)(p0 + o3);

#pragma unroll
    for (int st = 0; st < NST; ++st) {
        half8 G0, G1, G2, G3;
        if (st < NST - 1) {
            const _Float16* pn = p0 + (st + 1) * 64;
            G0 = *(const half8*)(pn);
            G1 = *(const half8*)(pn + o1);
            G2 = *(const half8*)(pn + o2);
            G3 = *(const half8*)(pn + o3);
        }
        const half8 wf = *(const half8*)(wls + st * 64 + (w * 2 + hi) * 8);
        half8 f0 = F0 * wf;
        half8 f1 = F1 * wf;
        half8 f2 = F2 * wf;
        half8 f3 = F3 * wf;
        a00 = __builtin_amdgcn_mfma_f32_32x32x16_f16(f0, f0, a00, 0, 0, 0);
        a01 = __builtin_amdgcn_mfma_f32_32x32x16_f16(f0, f1, a01, 0, 0, 0);
        a02 = __builtin_amdgcn_mfma_f32_32x32x16_f16(f0, f2, a02, 0, 0, 0);
        a03 = __builtin_amdgcn_mfma_f32_32x32x16_f16(f0, f3, a03, 0, 0, 0);
        a11 = __builtin_amdgcn_mfma_f32_32x32x16_f16(f1, f1, a11, 0, 0, 0);
        a12 = __builtin_amdgcn_mfma_f32_32x32x16_f16(f1, f2, a12, 0, 0, 0);
        a13 = __builtin_amdgcn_mfma_f32_32x32x16_f16(f1, f3, a13, 0, 0, 0);
        a22 = __builtin_amdgcn_mfma_f32_32x32x16_f16(f2, f2, a22, 0, 0, 0);
        a23 = __builtin_amdgcn_mfma_f32_32x32x16_f16(f2, f3, a23, 0, 0, 0);
        a33 = __builtin_amdgcn_mfma_f32_32x32x16_f16(f3, f3, a33, 0, 0, 0);
        if (st < NST - 1) { F0 = G0; F1 = G1; F2 = G2; F3 = G3; }
    }

    // ---- epilogue: [c2][lane] conflict-free reduce to fp16 partials ----
    float* Rb = (float*)smem;
    _Float16* Gp = (_Float16*)(ws + GP_OFF) + (size_t)(b * NCHUNK + chunk) * 10240;

#define WR(A_, r_) {                                                           \
        *(float4*)(Rb + (r_) * 1024 +   0 + l * 4) = make_float4(A_[0],  A_[1],  A_[2],  A_[3]);  \
        *(float4*)(Rb + (r_) * 1024 + 256 + l * 4) = make_float4(A_[4],  A_[5],  A_[6],  A_[7]);  \
        *(float4*)(Rb + (r_) * 1024 + 512 + l * 4) = make_float4(A_[8],  A_[9],  A_[10], A_[11]); \
        *(float4*)(Rb + (r_) * 1024 + 768 + l * 4) = make_float4(A_[12], A_[13], A_[14], A_[15]); }

#define RED(P_)                                                                \
    {                                                                          \
        __syncthreads();                                                       \
        _Pragma("unroll")                                                      \
        for (int pass = 0; pass < 2; ++pass) {                                 \
            const int off = tid * 4;                                           \
            float4 s0 = *(float4*)(Rb + (pass * 4 + 0) * 1024 + off);          \
            float4 s1 = *(float4*)(Rb + (pass * 4 + 1) * 1024 + off);          \
            float4 s2 = *(float4*)(Rb + (pass * 4 + 2) * 1024 + off);          \
            float4 s3 = *(float4*)(Rb + (pass * 4 + 3) * 1024 + off);          \
            half4 hv = { (_Float16)(s0.x + s1.x + s2.x + s3.x),                \
                         (_Float16)(s0.y + s1.y + s2.y + s3.y),                \
                         (_Float16)(s0.z + s1.z + s2.z + s3.z),                \
                         (_Float16)(s0.w + s1.w + s2.w + s3.w) };              \
            *(half4*)(Gp + (2 * (P_) + pass) * 1024 + off) = hv;               \
        }                                                                      \
        __syncthreads();                                                       \
    }

    WR(a00, w) WR(a01, 4 + w)
    RED(0)
    WR(a02, w) WR(a03, 4 + w)
    RED(1)
    WR(a11, w) WR(a12, 4 + w)
    RED(2)
    WR(a13, w) WR(a22, 4 + w)
    RED(3)
    WR(a23, w) WR(a33, 4 + w)
    RED(4)
#undef WR
#undef RED
}

// ---------------------------------------------------------------------------
// K2: wide reduce -> G f32 + sigma^2 I (validated R9/R10 decode) + m final sum.
// ---------------------------------------------------------------------------
__global__ __launch_bounds__(256) void reduce_kernel(
    const float* __restrict__ sig, unsigned char* __restrict__ ws)
{
    const int tid = threadIdx.x;
    const int b  = blockIdx.x / 5;
    const int t2 = blockIdx.x % 5;

    const int e_local = tid * 8;
    const int tile = t2 * 2 + (e_local >> 10);
    const int off0 = e_local & 1023;
    const int c2 = off0 >> 8;
    const int l0 = (off0 >> 2) & 63;

    static const int TT[10] = {0,0,0,0,1,1,1,2,2,3};
    static const int UU[10] = {0,1,2,3,1,2,3,2,3,3};
    const int tt = TT[tile], uu = UU[tile];

    const _Float16* Gp = (const _Float16*)(ws + GP_OFF)
                       + (size_t)b * NCHUNK * 10240 + (size_t)t2 * 2048 + e_local;
    float s[8] = {0.f,0.f,0.f,0.f,0.f,0.f,0.f,0.f};
#pragma unroll
    for (int ch = 0; ch < NCHUNK; ++ch) {
        half8 v = *(const half8*)(Gp + (size_t)ch * 10240);
#pragma unroll
        for (int j = 0; j < 8; ++j) s[j] += (float)v[j];
    }

    float* G = (float*)(ws + G_OFF) + (size_t)b * 16384;
    const float sg = sig[0];
#pragma unroll
    for (int j = 0; j < 8; ++j) {
        const int ll = l0 + (j >> 2);
        const int rj = j & 3;
        const int row = rj + 8 * c2 + 4 * (ll >> 5);
        const int col = ll & 31;
        const int Rr = tt * 32 + row;
        const int C  = uu * 32 + col;
        float v = s[j];
        G[Rr * KK + C] = (Rr == C) ? v + sg : v;
        if (tt != uu) G[C * KK + Rr] = v;
    }

    // m final sum (one block set per batch)
    if (t2 == 0 && tid < KK) {
        const float* src = (const float*)(ws + MP2_OFF) + ((size_t)b * KK + tid) * 256;
        float msum = 0.f;
#pragma unroll
        for (int c = 0; c < 64; ++c) {
            float4 v = *(const float4*)(src + c * 4);
            msum += (v.x + v.y) + (v.z + v.w);
        }
        ((float*)(ws + MG_OFF))[b * KK + tid] = msum;
    }
}

// ---------------------------------------------------------------------------
// K3: CG solve, unspilled: thread (i = tid&127, h = tid>>7) holds Gr[64].
// ---------------------------------------------------------------------------
__device__ __forceinline__ float blockDot4(float a, float bvl, float* red)
{
    float v = a * bvl;
#pragma unroll
    for (int off = 32; off > 0; off >>= 1) v += __shfl_down(v, off, 64);
    const int wid = threadIdx.x >> 6;
    if ((threadIdx.x & 63) == 0) red[wid] = v;
    __syncthreads();
    float s = (red[0] + red[1]) + (red[2] + red[3]);
    __syncthreads();
    return s;
}

__global__ __launch_bounds__(256, 1) void solve_kernel(
    const unsigned char* __restrict__ ws, float* __restrict__ out)
{
    __shared__ float ps[KK];
    __shared__ float qex[256];
    __shared__ float red[4];

    const int tid = threadIdx.x;
    const int b   = blockIdx.x;
    const int i   = tid & 127;
    const int h   = tid >> 7;

    const float* G = (const float*)(ws + G_OFF) + (size_t)b * 16384;

    float Gr[64];
#pragma unroll
    for (int j = 0; j < 64; ++j) Gr[j] = G[(size_t)(h * 64 + j) * KK + i];

    const float mvv = ((const float*)(ws + MG_OFF))[b * KK + i];

    float x = 0.f, r = mvv, p = r;
    ps[i] = p;
    float rs = blockDot4(r, r, red);

    for (int it = 0; it < NITER; ++it) {
        float q0 = 0.f, q1 = 0.f, q2 = 0.f, q3 = 0.f;
        const float* psh = ps + h * 64;
#pragma unroll
        for (int u = 0; u < 16; ++u) {
            float4 pv = *(const float4*)(psh + 4 * u);
            q0 = fmaf(Gr[4 * u + 0], pv.x, q0);
            q1 = fmaf(Gr[4 * u + 1], pv.y, q1);
            q2 = fmaf(Gr[4 * u + 2], pv.z, q2);
            q3 = fmaf(Gr[4 * u + 3], pv.w, q3);
        }
        qex[tid] = (q0 + q1) + (q2 + q3);
        __syncthreads();
        const float q = qex[i] + qex[128 + i];

        float pq    = blockDot4(p, q, red);
        float alpha = rs / (pq + 1e-30f);
        x = fmaf(alpha, p, x);
        r = fmaf(-alpha, q, r);
        float rs2  = blockDot4(r, r, red);
        float beta = rs2 / (rs + 1e-30f);
        rs = rs2;
        p  = fmaf(beta, p, r);
        __syncthreads();
        ps[i] = p;
        __syncthreads();
    }
    if (h == 0) out[(size_t)b * KK + i] = x;
}

// ---------------------------------------------------------------------------
extern "C" void kernel_launch(void* const* d_in, const int* in_sizes, int n_in,
                              void* d_out, int out_size, void* d_ws, size_t ws_size,
                              hipStream_t stream)
{
    const float* data = (const float*)d_in[0];
    const float* mask = (const float*)d_in[1];
    const float* mult = (const float*)d_in[2];
    const float* sig  = (const float*)d_in[3];
    unsigned char* ws = (unsigned char*)d_ws;
    float* out = (float*)d_out;

    prep_kernel  <<<256, 256, 0, stream>>>(data, mask, mult, ws);
    gram_kernel  <<<BATCH * NCHUNK, 256, 0, stream>>>(ws);
    reduce_kernel<<<BATCH * 5, 256, 0, stream>>>(sig, ws);
    solve_kernel <<<BATCH, 256, 0, stream>>>(ws, out);
}